// Round 1
// 626.560 us; speedup vs baseline: 1.0626x; 1.0626x over previous
//
#include <hip/hip_runtime.h>

#define N_ATOMS   100000
#define N_BONDS   220000
#define N_MESS    20000
#define N_MSG     (N_MESS + N_BONDS)        // 240000
#define ATOM_FDIM 35
#define BOND_FDIM 5
#define BOND_IN   (ATOM_FDIM + BOND_FDIM)   // 40
#define H         128
#define MAX_NB    10
#define DEPTH     6
#define KO        (ATOM_FDIM + H)           // 163
#define KC        192                       // padded K for both GEMMs

typedef __attribute__((ext_vector_type(8))) short short8;   // 8 bf16 (4 VGPRs)
typedef __attribute__((ext_vector_type(4))) float f32x4;    // MFMA C/D frag

static __device__ __forceinline__ unsigned short f2bf(float f) {
    union { float f; unsigned int i; } v; v.f = f;
    unsigned int x = v.i;
    return (unsigned short)((x + 0x7FFFu + ((x >> 16) & 1u)) >> 16);
}

// byte b of u32 -> float; clang folds to v_cvt_f32_ubyte{0..3}
static __device__ __forceinline__ float ub2f(unsigned int v, int b) {
    return (float)((v >> (b * 8)) & 0xffu);
}

static __device__ __forceinline__ unsigned char q8(float x) {
    int q = __float2int_rn(x);
    q = q < 0 ? 0 : (q > 255 ? 255 : q);
    return (unsigned char)q;
}

// ---------------------------------------------------------------------------
// prep: fbonds->bf16, weight transposes, out zeroing. (message tables now
// handled by qtree + quantizing producers)
// ---------------------------------------------------------------------------
#define PTa (N_BONDS * BOND_IN)             // 8,800,000  (fbc)
#define PTb (PTa + H * KC)                  // + 24576    (WT)
#define PTc (PTb + H * KC)                  // + 24576    (WoT)

__global__ __launch_bounds__(256) void prep(
    const float* __restrict__ fbonds,
    const float* __restrict__ Wi, const float* __restrict__ Wh,
    const float* __restrict__ Wo,
    ushort* __restrict__ fbc, ushort* __restrict__ WT,
    ushort* __restrict__ WoT, float* __restrict__ out, int n_out)
{
    int i = blockIdx.x * 256 + threadIdx.x;
    if (i < PTa) {
        fbc[i] = f2bf(fbonds[i]);
    } else if (i < PTb) {
        int j = i - PTa;
        int n = j / KC, k = j - n * KC;
        float v = (k < BOND_IN) ? Wi[k * H + n]
                : (k < BOND_IN + H) ? Wh[(k - BOND_IN) * H + n] : 0.f;
        WT[j] = f2bf(v);
    } else if (i < PTc) {
        int j = i - PTb;
        int n = j / KC, k = j - n * KC;
        float v = (k < H) ? Wo[(ATOM_FDIM + k) * H + n]
                : (k < KO) ? Wo[(k - H) * H + n] : 0.f;
        WoT[j] = f2bf(v);
    } else {
        int j = i - PTc;
        if (j < n_out) out[j] = 0.f;
    }
}

// ---------------------------------------------------------------------------
// qtree: affine-u8 quantize tree messages (signed data -> offset=rowmin)
// into both tables. One row per wave.
// ---------------------------------------------------------------------------
__global__ __launch_bounds__(256) void qtree(
    const float* __restrict__ tree,
    unsigned char* __restrict__ qA, unsigned char* __restrict__ qB,
    float2* __restrict__ sA, float2* __restrict__ sB)
{
    int row = blockIdx.x * 4 + (threadIdx.x >> 6);
    int lane = threadIdx.x & 63;
    float2 v = *(const float2*)&tree[(size_t)row * H + lane * 2];
    float mx = fmaxf(v.x, v.y), mn = fminf(v.x, v.y);
    #pragma unroll
    for (int d = 1; d <= 32; d <<= 1) {
        mx = fmaxf(mx, __shfl_xor(mx, d));
        mn = fminf(mn, __shfl_xor(mn, d));
    }
    float rng = mx - mn;
    float inv = (rng > 0.f) ? 255.f / rng : 0.f;
    int q0 = q8((v.x - mn) * inv);
    int q1 = q8((v.y - mn) * inv);
    unsigned short pk = (unsigned short)(q0 | (q1 << 8));
    ((unsigned short*)qA)[(size_t)row * 64 + lane] = pk;
    ((unsigned short*)qB)[(size_t)row * 64 + lane] = pk;
    if (lane == 0) {
        float2 s = make_float2(rng * (1.f / 255.f), mn);
        sA[row] = s; sB[row] = s;
    }
}

// ---------------------------------------------------------------------------
// gather8: sum 10 u8-quantized rows (128 B = 1 cache line each), this lane's
// 8 columns [c16*8, c16*8+8); dequant val = sc*q + off; return bf16-packed.
// ---------------------------------------------------------------------------
static __device__ __forceinline__ uint4 gather8(
    const unsigned char* __restrict__ msgq, const float2* __restrict__ scl,
    const int* __restrict__ gidx, int c16)
{
    int idx[MAX_NB];
    #pragma unroll
    for (int n = 0; n < MAX_NB; n++) idx[n] = gidx[n];
    float2 so[MAX_NB];
    uint2 d[MAX_NB];
    #pragma unroll
    for (int n = 0; n < MAX_NB; n++) {
        so[n] = scl[idx[n]];
        d[n] = *(const uint2*)(msgq + (size_t)idx[n] * H + c16 * 8);
    }
    float s0=0.f,s1=0.f,s2=0.f,s3=0.f,s4=0.f,s5=0.f,s6=0.f,s7=0.f;
    float off = 0.f;
    #pragma unroll
    for (int n = 0; n < MAX_NB; n++) {
        float sc = so[n].x; off += so[n].y;
        s0 += sc * ub2f(d[n].x, 0); s1 += sc * ub2f(d[n].x, 1);
        s2 += sc * ub2f(d[n].x, 2); s3 += sc * ub2f(d[n].x, 3);
        s4 += sc * ub2f(d[n].y, 0); s5 += sc * ub2f(d[n].y, 1);
        s6 += sc * ub2f(d[n].y, 2); s7 += sc * ub2f(d[n].y, 3);
    }
    s0 += off; s1 += off; s2 += off; s3 += off;
    s4 += off; s5 += off; s6 += off; s7 += off;
    uint4 pk;
    pk.x = ((unsigned)f2bf(s1) << 16) | (unsigned)f2bf(s0);
    pk.y = ((unsigned)f2bf(s3) << 16) | (unsigned)f2bf(s2);
    pk.z = ((unsigned)f2bf(s5) << 16) | (unsigned)f2bf(s4);
    pk.w = ((unsigned)f2bf(s7) << 16) | (unsigned)f2bf(s6);
    return pk;
}

// ---------------------------------------------------------------------------
// quant_epilogue: relu + per-row u8 quantize (offset=0, rows are post-relu)
// row max via shfl_xor within each 16-lane group + small LDS cross-wave.
// ---------------------------------------------------------------------------
static __device__ __forceinline__ void quant_epilogue(
    f32x4 c00, f32x4 c01, f32x4 c10, f32x4 c11,
    int tid, int row_base,
    float* rmx, float* qp,
    unsigned char* __restrict__ gq, float2* __restrict__ scout)
{
    int lane = tid & 63, wv = tid >> 6;
    int m_lane = lane & 15, quad = lane >> 4;
    int n0 = wv * 32;

    float v00[4], v01[4], v10[4], v11[4];
    #pragma unroll
    for (int r = 0; r < 4; r++) {
        v00[r] = fmaxf(c00[r], 0.f); v01[r] = fmaxf(c01[r], 0.f);
        v10[r] = fmaxf(c10[r], 0.f); v11[r] = fmaxf(c11[r], 0.f);
    }
    #pragma unroll
    for (int r = 0; r < 4; r++) {
        float mx0 = fmaxf(v00[r], v01[r]);
        float mx1 = fmaxf(v10[r], v11[r]);
        #pragma unroll
        for (int d = 1; d <= 8; d <<= 1) {
            mx0 = fmaxf(mx0, __shfl_xor(mx0, d));
            mx1 = fmaxf(mx1, __shfl_xor(mx1, d));
        }
        if (m_lane == 0) {
            rmx[(quad * 4 + r) * 4 + wv]      = mx0;
            rmx[(quad * 4 + r + 16) * 4 + wv] = mx1;
        }
    }
    __syncthreads();
    if (tid < 32) {
        float mx = fmaxf(fmaxf(rmx[tid * 4], rmx[tid * 4 + 1]),
                         fmaxf(rmx[tid * 4 + 2], rmx[tid * 4 + 3]));
        qp[tid] = (mx > 0.f) ? 255.f / mx : 0.f;
        scout[row_base + tid] = make_float2(mx * (1.f / 255.f), 0.f);
    }
    __syncthreads();
    #pragma unroll
    for (int r = 0; r < 4; r++) {
        int r0 = quad * 4 + r, r1 = r0 + 16;
        float i0 = qp[r0], i1 = qp[r1];
        gq[(size_t)(row_base + r0) * H + n0 + m_lane]      = q8(v00[r] * i0);
        gq[(size_t)(row_base + r0) * H + n0 + 16 + m_lane] = q8(v01[r] * i0);
        gq[(size_t)(row_base + r1) * H + n0 + m_lane]      = q8(v10[r] * i1);
        gq[(size_t)(row_base + r1) * H + n0 + 16 + m_lane] = q8(v11[r] * i1);
    }
}

// ---------------------------------------------------------------------------
// binput0 (MFMA): graph0 = relu(fbonds @ W_i) -> u8 rowscale. K cut to 64.
// ---------------------------------------------------------------------------
__global__ __launch_bounds__(256, 4) void binput0(
    const ushort* __restrict__ fbc, const ushort* __restrict__ WT,
    unsigned char* __restrict__ gq_out, float2* __restrict__ sc_out)
{
    __shared__ ushort Xlds[32 * 25 * 8];
    __shared__ float rmx[32 * 4];
    __shared__ float qp[32];

    int tid = threadIdx.x;
    int bond0 = blockIdx.x * 32;           // grid = 6875, exact
    int lane = tid & 63, wv = tid >> 6;

    if (tid < 160) {                       // b = tid/5, k8 = tid%5
        int b = tid / 5, k8 = tid - b * 5;
        *(short8*)&Xlds[(b * 25 + k8) * 8] =
            *(const short8*)&fbc[(size_t)bond0 * BOND_IN + tid * 8];
    }
    if (tid < 96) {                        // zero k in [40,64): cells 5..7
        int b = tid / 3, k8 = 5 + (tid - b * 3);
        *(float4*)&Xlds[(b * 25 + k8) * 8] = float4{0.f, 0.f, 0.f, 0.f};
    }
    __syncthreads();

    int n0 = wv * 32;
    int m_lane = lane & 15, quad = lane >> 4;
    f32x4 c00 = {0,0,0,0}, c01 = {0,0,0,0}, c10 = {0,0,0,0}, c11 = {0,0,0,0};

    #pragma unroll
    for (int s = 0; s < 2; s++) {          // K = 64 covers fb (k<40) + zeros
        short8 a0 = *(const short8*)&Xlds[((m_lane)      * 25 + s * 4 + quad) * 8];
        short8 a1 = *(const short8*)&Xlds[((16 + m_lane) * 25 + s * 4 + quad) * 8];
        short8 b0 = *(const short8*)&WT[(size_t)(n0 + m_lane)      * KC + s * 32 + quad * 8];
        short8 b1 = *(const short8*)&WT[(size_t)(n0 + 16 + m_lane) * KC + s * 32 + quad * 8];
        c00 = __builtin_amdgcn_mfma_f32_16x16x32_bf16(a0, b0, c00, 0, 0, 0);
        c01 = __builtin_amdgcn_mfma_f32_16x16x32_bf16(a0, b1, c01, 0, 0, 0);
        c10 = __builtin_amdgcn_mfma_f32_16x16x32_bf16(a1, b0, c10, 0, 0, 0);
        c11 = __builtin_amdgcn_mfma_f32_16x16x32_bf16(a1, b1, c11, 0, 0, 0);
    }

    quant_epilogue(c00, c01, c10, c11, tid, bond0, rmx, qp, gq_out, sc_out);
}

// ---------------------------------------------------------------------------
// mp_round (MFMA): graph_out[b] = relu([fb[b]|nei[b]|0] @ [Wi;Wh;0])
// Messages u8-rowscale: gathered row = 128 B = one cache line; scale table
// L2-resident. Output re-quantized per row in the epilogue.
// ---------------------------------------------------------------------------
__global__ __launch_bounds__(256, 4) void mp_round(
    const unsigned char* __restrict__ msg_in, const float2* __restrict__ sc_in,
    const ushort* __restrict__ fbc, const int* __restrict__ bgraph,
    const ushort* __restrict__ WT,
    unsigned char* __restrict__ gq_out, float2* __restrict__ sc_out)
{
    __shared__ ushort Xlds[32 * 25 * 8];   // 800 cells x 16 B = 12800 B
    __shared__ float rmx[32 * 4];
    __shared__ float qp[32];

    int tid = threadIdx.x;
    int bond0 = blockIdx.x * 32;           // grid = 6875, exact
    int lane = tid & 63, wv = tid >> 6;
    int q = lane >> 4, c16 = lane & 15;

    // stage fb tile (pre-converted bf16): 160 x 16 B copies
    if (tid < 160) {
        int b = tid / 5, k8 = tid - b * 5;
        *(short8*)&Xlds[(b * 25 + k8) * 8] =
            *(const short8*)&fbc[(size_t)bond0 * BOND_IN + tid * 8];
    }
    // zero pad k in [168,192): cells 21..23
    if (tid < 96) {
        int b = tid / 3, k8 = 21 + (tid - b * 3);
        *(float4*)&Xlds[(b * 25 + k8) * 8] = float4{0.f, 0.f, 0.f, 0.f};
    }
    // gather nei: wave wv covers rows wv+4t, t = g*4+q; lane sums elements
    // [c16*8, c16*8+8) of its row -> cell 5+c16.
    #pragma unroll
    for (int g = 0; g < 2; g++) {
        int b = wv + 4 * (g * 4 + q);
        uint4 pk = gather8(msg_in, sc_in, bgraph + (size_t)(bond0 + b) * MAX_NB, c16);
        *(uint4*)&Xlds[(b * 25 + 5 + c16) * 8] = pk;
    }
    __syncthreads();

    int n0 = wv * 32;
    int m_lane = lane & 15, quad = lane >> 4;
    f32x4 c00 = {0,0,0,0}, c01 = {0,0,0,0}, c10 = {0,0,0,0}, c11 = {0,0,0,0};

    #pragma unroll
    for (int s = 0; s < KC / 32; s++) {
        short8 a0 = *(const short8*)&Xlds[((m_lane)      * 25 + s * 4 + quad) * 8];
        short8 a1 = *(const short8*)&Xlds[((16 + m_lane) * 25 + s * 4 + quad) * 8];
        short8 b0 = *(const short8*)&WT[(size_t)(n0 + m_lane)      * KC + s * 32 + quad * 8];
        short8 b1 = *(const short8*)&WT[(size_t)(n0 + 16 + m_lane) * KC + s * 32 + quad * 8];
        c00 = __builtin_amdgcn_mfma_f32_16x16x32_bf16(a0, b0, c00, 0, 0, 0);
        c01 = __builtin_amdgcn_mfma_f32_16x16x32_bf16(a0, b1, c01, 0, 0, 0);
        c10 = __builtin_amdgcn_mfma_f32_16x16x32_bf16(a1, b0, c10, 0, 0, 0);
        c11 = __builtin_amdgcn_mfma_f32_16x16x32_bf16(a1, b1, c11, 0, 0, 0);
    }

    quant_epilogue(c00, c01, c10, c11, tid, bond0, rmx, qp, gq_out, sc_out);
}

// ---------------------------------------------------------------------------
// atom_mfma: relu([nei|fatoms|0] @ WoT^T + b_o), then per-molecule partial
// sums reduced in LDS and atomicAdd'ed into out. Gather path now u8.
// ---------------------------------------------------------------------------
__global__ __launch_bounds__(256, 4) void atom_mfma(
    const float* __restrict__ fatoms, const unsigned char* __restrict__ msg,
    const float2* __restrict__ scl,
    const int* __restrict__ agraph, const ushort* __restrict__ WoT,
    const float* __restrict__ bo, const int* __restrict__ mol_ids,
    float* __restrict__ out)
{
    __shared__ ushort Xlds[32 * 25 * 8];
    __shared__ float htile[32 * H];
    __shared__ int mlds[32];

    int tid = threadIdx.x;
    int a0 = blockIdx.x * 32;              // grid = 3125, exact
    int lane = tid & 63, wv = tid >> 6;
    int q = lane >> 4, c16 = lane & 15;

    // fatoms: k in [128,163)
    for (int i = tid; i < 32 * ATOM_FDIM; i += 256) {
        int b = i / ATOM_FDIM, t = i - b * ATOM_FDIM;
        int k = H + t;
        Xlds[(b * 25 + (k >> 3)) * 8 + (k & 7)] = f2bf(fatoms[(size_t)a0 * ATOM_FDIM + i]);
    }
    // zero k in [163,168)
    if (tid < 160) {
        int b = tid / 5, k = 163 + (tid - b * 5);
        Xlds[(b * 25 + (k >> 3)) * 8 + (k & 7)] = 0;
    }
    // zero cells 21..23 (k in [168,192))
    if (tid < 96) {
        int b = tid / 3, k8 = 21 + (tid - b * 3);
        *(float4*)&Xlds[(b * 25 + k8) * 8] = float4{0.f, 0.f, 0.f, 0.f};
    }
    if (tid < 32) mlds[tid] = mol_ids[a0 + tid];
    // gather nei: k in [0,128) -> cell c16
    #pragma unroll
    for (int g = 0; g < 2; g++) {
        int b = wv + 4 * (g * 4 + q);
        uint4 pk = gather8(msg, scl, agraph + (size_t)(a0 + b) * MAX_NB, c16);
        *(uint4*)&Xlds[(b * 25 + c16) * 8] = pk;
    }
    __syncthreads();

    int n0 = wv * 32;
    int m_lane = lane & 15, quad = lane >> 4;
    float bias0 = bo[n0 + m_lane], bias1 = bo[n0 + 16 + m_lane];
    f32x4 c00 = {bias0, bias0, bias0, bias0};
    f32x4 c01 = {bias1, bias1, bias1, bias1};
    f32x4 c10 = {bias0, bias0, bias0, bias0};
    f32x4 c11 = {bias1, bias1, bias1, bias1};

    #pragma unroll
    for (int s = 0; s < KC / 32; s++) {
        short8 a0f = *(const short8*)&Xlds[((m_lane)      * 25 + s * 4 + quad) * 8];
        short8 a1f = *(const short8*)&Xlds[((16 + m_lane) * 25 + s * 4 + quad) * 8];
        short8 b0f = *(const short8*)&WoT[(size_t)(n0 + m_lane)      * KC + s * 32 + quad * 8];
        short8 b1f = *(const short8*)&WoT[(size_t)(n0 + 16 + m_lane) * KC + s * 32 + quad * 8];
        c00 = __builtin_amdgcn_mfma_f32_16x16x32_bf16(a0f, b0f, c00, 0, 0, 0);
        c01 = __builtin_amdgcn_mfma_f32_16x16x32_bf16(a0f, b1f, c01, 0, 0, 0);
        c10 = __builtin_amdgcn_mfma_f32_16x16x32_bf16(a1f, b0f, c10, 0, 0, 0);
        c11 = __builtin_amdgcn_mfma_f32_16x16x32_bf16(a1f, b1f, c11, 0, 0, 0);
    }

    #pragma unroll
    for (int r = 0; r < 4; r++) {
        int r0 = quad * 4 + r, r1 = r0 + 16;
        htile[r0 * H + n0 + m_lane]      = fmaxf(c00[r], 0.f);
        htile[r0 * H + n0 + 16 + m_lane] = fmaxf(c01[r], 0.f);
        htile[r1 * H + n0 + m_lane]      = fmaxf(c10[r], 0.f);
        htile[r1 * H + n0 + 16 + m_lane] = fmaxf(c11[r], 0.f);
    }
    __syncthreads();

    // segmented reduce over the 32-atom tile, one atomicAdd per (segment,col)
    if (tid < H) {
        int j = tid;
        float acc = 0.f;
        int cur = mlds[0];
        for (int r = 0; r < 32; r++) {
            int m = mlds[r];
            if (m != cur) {
                atomicAdd(&out[(size_t)cur * H + j], acc);
                acc = 0.f; cur = m;
            }
            acc += htile[r * H + j];
        }
        atomicAdd(&out[(size_t)cur * H + j], acc);
    }
}

// ---------------------------------------------------------------------------
// pool_div: out[m] /= count(m)  (counts via binary search on sorted mol_ids)
// ---------------------------------------------------------------------------
__global__ __launch_bounds__(128) void pool_div(
    const int* __restrict__ mol_ids, float* __restrict__ out, int n_atoms)
{
    int m = blockIdx.x;
    int j = threadIdx.x;

    int lo = 0, hi = n_atoms;
    while (lo < hi) { int mid = (lo + hi) >> 1; if (mol_ids[mid] < m) lo = mid + 1; else hi = mid; }
    int start = lo;
    hi = n_atoms;
    while (lo < hi) { int mid = (lo + hi) >> 1; if (mol_ids[mid] < m + 1) lo = mid + 1; else hi = mid; }
    int end = lo;

    out[(size_t)m * H + j] /= fmaxf((float)(end - start), 1.f);
}

// ---------------------------------------------------------------------------
extern "C" void kernel_launch(void* const* d_in, const int* in_sizes, int n_in,
                              void* d_out, int out_size, void* d_ws, size_t ws_size,
                              hipStream_t stream)
{
    const float* fatoms  = (const float*)d_in[0];
    const float* fbonds  = (const float*)d_in[1];
    const float* tree    = (const float*)d_in[2];
    const int*   agraph  = (const int*)d_in[3];
    const int*   bgraph  = (const int*)d_in[4];
    const int*   mol_ids = (const int*)d_in[5];
    const float* W_i = (const float*)d_in[7];
    const float* W_h = (const float*)d_in[8];
    const float* W_o = (const float*)d_in[9];
    const float* b_o = (const float*)d_in[10];
    float* out = (float*)d_out;

    // ws: mqA | mqB (u8, 30.72 MB each) | scA | scB (float2, 1.92 MB each)
    //     | WT | WoT (48 KB each) | fbc (17.6 MB)   -- total ~83 MB
    unsigned char* mqA = (unsigned char*)d_ws;
    unsigned char* mqB = mqA + (size_t)N_MSG * H;
    float2* scA = (float2*)(mqB + (size_t)N_MSG * H);
    float2* scB = scA + N_MSG;
    ushort* WT  = (ushort*)(scB + N_MSG);
    ushort* WoT = WT + (size_t)H * KC;
    ushort* fbc = WoT + (size_t)H * KC;

    int prep_total = PTc + out_size;
    prep<<<(prep_total + 255) / 256, 256, 0, stream>>>(
        fbonds, W_i, W_h, W_o, fbc, WT, WoT, out, out_size);

    qtree<<<N_MESS / 4, 256, 0, stream>>>(tree, mqA, mqB, scA, scB);

    binput0<<<N_BONDS / 32, 256, 0, stream>>>(fbc, WT,
        mqA + (size_t)N_MESS * H, scA + N_MESS);

    const unsigned char* tin = mqA; const float2* sin = scA;
    unsigned char* tout = mqB; float2* sout = scB;
    for (int r = 0; r < DEPTH - 1; r++) {
        mp_round<<<N_BONDS / 32, 256, 0, stream>>>(tin, sin, fbc, bgraph, WT,
            tout + (size_t)N_MESS * H, sout + N_MESS);
        const unsigned char* t1 = tin; tin = tout; tout = (unsigned char*)t1;
        const float2* t2 = sin; sin = sout; sout = (float2*)t2;
    }
    // after 5 rounds the final message table is msgB (== tin)

    atom_mfma<<<N_ATOMS / 32, 256, 0, stream>>>(fatoms, tin, sin, agraph, WoT, b_o,
                                                mol_ids, out);

    int n_mols = out_size / H;
    pool_div<<<n_mols, 128, 0, stream>>>(mol_ids, out, N_ATOMS);
}

// Round 2
// 543.447 us; speedup vs baseline: 1.2251x; 1.1529x over previous
//
#include <hip/hip_runtime.h>

#define N_ATOMS   100000
#define N_BONDS   220000
#define N_MESS    20000
#define N_MSG     (N_MESS + N_BONDS)        // 240000
#define ATOM_FDIM 35
#define BOND_FDIM 5
#define BOND_IN   (ATOM_FDIM + BOND_FDIM)   // 40
#define H         128
#define MAX_NB    10
#define NB_PAD    12                        // padded stride for 16B-aligned idx loads
#define DEPTH     6
#define KO        (ATOM_FDIM + H)           // 163
#define KC        192                       // padded K for both GEMMs
#define SC_BIAS   887u                      // scale code bias: scf = asf((code+887)<<20)

typedef __attribute__((ext_vector_type(8))) short short8;   // 8 bf16 (4 VGPRs)
typedef __attribute__((ext_vector_type(4))) float f32x4;    // MFMA C/D frag

static __device__ __forceinline__ float asf(unsigned int u) {
    union { unsigned int i; float f; } v; v.i = u; return v.f;
}

static __device__ __forceinline__ unsigned short f2bf(float f) {
    union { float f; unsigned int i; } v; v.f = f;
    unsigned int x = v.i;
    return (unsigned short)((x + 0x7FFFu + ((x >> 16) & 1u)) >> 16);
}

// signed 7-bit field at bit p of w (p in {0,7,14,21}) -> v_bfe_i32
static __device__ __forceinline__ int bfe7(unsigned int w, int p) {
    return ((int)(w << (25 - p))) >> 25;
}

// bytes of dword (q values as i8) -> packed 4x7-bit at bits 0..27
static __device__ __forceinline__ unsigned int pack7(unsigned int d) {
    return (d & 0x7Fu) | ((d >> 8) & 0x7Fu) << 7 |
           ((d >> 16) & 0x7Fu) << 14 | ((d >> 24) & 0x7Fu) << 21;
}

// ---------------------------------------------------------------------------
// prep: fbonds->bf16, weight transposes, graph padding 10->12, out zeroing.
// ---------------------------------------------------------------------------
#define PTa (N_BONDS * BOND_IN)             // fbc
#define PTb (PTa + H * KC)                  // WT
#define PTc (PTb + H * KC)                  // WoT
#define PTd (PTc + N_BONDS * MAX_NB)        // bgraphP
#define PTe (PTd + N_ATOMS * MAX_NB)        // agraphP

__global__ __launch_bounds__(256) void prep(
    const float* __restrict__ fbonds,
    const float* __restrict__ Wi, const float* __restrict__ Wh,
    const float* __restrict__ Wo,
    const int* __restrict__ bgraph, const int* __restrict__ agraph,
    ushort* __restrict__ fbc, ushort* __restrict__ WT,
    ushort* __restrict__ WoT,
    int* __restrict__ bgP, int* __restrict__ agP,
    float* __restrict__ out, int n_out)
{
    int i = blockIdx.x * 256 + threadIdx.x;
    if (i < PTa) {
        fbc[i] = f2bf(fbonds[i]);
    } else if (i < PTb) {
        int j = i - PTa;
        int n = j / KC, k = j - n * KC;
        float v = (k < BOND_IN) ? Wi[k * H + n]
                : (k < BOND_IN + H) ? Wh[(k - BOND_IN) * H + n] : 0.f;
        WT[j] = f2bf(v);
    } else if (i < PTc) {
        int j = i - PTb;
        int n = j / KC, k = j - n * KC;
        float v = (k < H) ? Wo[(ATOM_FDIM + k) * H + n]
                : (k < KO) ? Wo[(k - H) * H + n] : 0.f;
        WoT[j] = f2bf(v);
    } else if (i < PTd) {
        int j = i - PTc;
        int b = j / MAX_NB, n = j - b * MAX_NB;
        bgP[b * NB_PAD + n] = bgraph[j];
    } else if (i < PTe) {
        int j = i - PTd;
        int a = j / MAX_NB, n = j - a * MAX_NB;
        agP[a * NB_PAD + n] = agraph[j];
    } else {
        int j = i - PTe;
        if (j < n_out) out[j] = 0.f;
    }
}

// ---------------------------------------------------------------------------
// qtree: quantize tree rows into the packed i7+e8 line format, both tables.
// One 8-col slot per thread. Row 0 (zero padding message) stays all-zero.
// ---------------------------------------------------------------------------
__global__ __launch_bounds__(256) void qtree(
    const float* __restrict__ tree,
    uint2* __restrict__ qA, uint2* __restrict__ qB)
{
    int t = blockIdx.x * 256 + threadIdx.x;     // 20000*16 slots
    int row = t >> 4, L = t & 15;
    float4 a = *(const float4*)&tree[(size_t)row * H + L * 8];
    float4 b = *(const float4*)&tree[(size_t)row * H + L * 8 + 4];
    float m8 = fmaxf(fmaxf(fmaxf(fabsf(a.x), fabsf(a.y)), fmaxf(fabsf(a.z), fabsf(a.w))),
                     fmaxf(fmaxf(fabsf(b.x), fabsf(b.y)), fmaxf(fabsf(b.z), fabsf(b.w))));
    float t_ = m8 * (1.f / 63.f);
    int code = (int)((__float_as_uint(t_) + 0xFFFFFu) >> 20) - (int)SC_BIAS;
    code = code < 1 ? 1 : (code > 255 ? 255 : code);
    float inv = __builtin_amdgcn_rcpf(asf(((unsigned)code + SC_BIAS) << 20));
    int q[8];
    float v[8] = {a.x, a.y, a.z, a.w, b.x, b.y, b.z, b.w};
    #pragma unroll
    for (int k = 0; k < 8; k++) {
        int qq = __float2int_rn(v[k] * inv);
        q[k] = qq < -63 ? -63 : (qq > 63 ? 63 : qq);
    }
    unsigned lo = (q[0] & 0x7F) | (q[1] & 0x7F) << 7 | (q[2] & 0x7F) << 14 |
                  (q[3] & 0x7F) << 21 | ((unsigned)code & 0xF) << 28;
    unsigned hi = (q[4] & 0x7F) | (q[5] & 0x7F) << 7 | (q[6] & 0x7F) << 14 |
                  (q[7] & 0x7F) << 21 | ((unsigned)code >> 4) << 28;
    uint2 pk = {lo, hi};
    qA[t] = pk; qB[t] = pk;
}

// ---------------------------------------------------------------------------
// gather7: sum 10 packed rows (self-contained 128 B lines: 7-bit values +
// in-line e8 scale, NO scale-table load). Indices via 3 aligned vector loads
// from the padded graph. Returns bf16-packed sums for this lane's 8 cols.
// ---------------------------------------------------------------------------
static __device__ __forceinline__ uint4 gather7(
    const uint2* __restrict__ msgq, const int* __restrict__ gidx, int c16)
{
    uint4 i0 = *(const uint4*)gidx;
    uint4 i1 = *(const uint4*)(gidx + 4);
    uint2 i2 = *(const uint2*)(gidx + 8);
    int idx[MAX_NB] = {(int)i0.x, (int)i0.y, (int)i0.z, (int)i0.w,
                       (int)i1.x, (int)i1.y, (int)i1.z, (int)i1.w,
                       (int)i2.x, (int)i2.y};
    uint2 d[MAX_NB];
    #pragma unroll
    for (int n = 0; n < MAX_NB; n++)
        d[n] = msgq[(size_t)idx[n] * 16 + c16];
    float s0=0.f,s1=0.f,s2=0.f,s3=0.f,s4=0.f,s5=0.f,s6=0.f,s7=0.f;
    #pragma unroll
    for (int n = 0; n < MAX_NB; n++) {
        unsigned lo = d[n].x, hi = d[n].y;
        unsigned code = (lo >> 28) | ((hi >> 28) << 4);
        float scf = asf((code + SC_BIAS) << 20);
        s0 += scf * (float)bfe7(lo, 0);
        s1 += scf * (float)bfe7(lo, 7);
        s2 += scf * (float)bfe7(lo, 14);
        s3 += scf * (float)bfe7(lo, 21);
        s4 += scf * (float)bfe7(hi, 0);
        s5 += scf * (float)bfe7(hi, 7);
        s6 += scf * (float)bfe7(hi, 14);
        s7 += scf * (float)bfe7(hi, 21);
    }
    uint4 pk;
    pk.x = ((unsigned)f2bf(s1) << 16) | (unsigned)f2bf(s0);
    pk.y = ((unsigned)f2bf(s3) << 16) | (unsigned)f2bf(s2);
    pk.z = ((unsigned)f2bf(s5) << 16) | (unsigned)f2bf(s4);
    pk.w = ((unsigned)f2bf(s7) << 16) | (unsigned)f2bf(s6);
    return pk;
}

// ---------------------------------------------------------------------------
// quant_epilogue7: relu + per-8-col-group i7 quantize. Group max = 3-step
// shfl_xor octet butterfly (no LDS row-max dance, no extra syncthreads pair);
// bytes staged in LDS and repacked 2 slots/thread into 16 B stores.
// ---------------------------------------------------------------------------
static __device__ __forceinline__ void quant_epilogue7(
    f32x4 c00, f32x4 c01, f32x4 c10, f32x4 c11,
    int tid, int row_base,
    unsigned int* qlds_u32 /*32*32 dwords*/, unsigned char* clds /*32*16*/,
    uint2* __restrict__ gq)
{
    int lane = tid & 63, wv = tid >> 6;
    int m_lane = lane & 15, quad = lane >> 4;
    int n0 = wv * 32;
    char* qlds = (char*)qlds_u32;

    #pragma unroll
    for (int st = 0; st < 4; st++) {
        #pragma unroll
        for (int r = 0; r < 4; r++) {
            float x = (st == 0) ? c00[r] : (st == 1) ? c01[r] : (st == 2) ? c10[r] : c11[r];
            x = fmaxf(x, 0.f);
            float mx = x;
            mx = fmaxf(mx, __shfl_xor(mx, 1));
            mx = fmaxf(mx, __shfl_xor(mx, 2));
            mx = fmaxf(mx, __shfl_xor(mx, 4));
            float t_ = mx * (1.f / 63.f);
            int code = (int)((__float_as_uint(t_) + 0xFFFFFu) >> 20) - (int)SC_BIAS;
            code = code < 1 ? 1 : (code > 255 ? 255 : code);
            float inv = __builtin_amdgcn_rcpf(asf(((unsigned)code + SC_BIAS) << 20));
            int q = __float2int_rn(x * inv);
            q = q > 63 ? 63 : q;                 // x >= 0 post-relu
            int row = quad * 4 + r + ((st & 2) ? 16 : 0);
            int col = n0 + m_lane + ((st & 1) ? 16 : 0);
            qlds[row * 128 + col] = (char)q;
            if ((m_lane & 7) == 0) clds[row * 16 + (col >> 3)] = (unsigned char)code;
        }
    }
    __syncthreads();
    {
        int s = tid * 2;                          // 512 slots: 32 rows x 16
        int row = s >> 4, grp = s & 15;           // grp even
        uint4 w = *(const uint4*)(qlds + row * 128 + grp * 8);
        unsigned code0 = clds[row * 16 + grp];
        unsigned code1 = clds[row * 16 + grp + 1];
        uint4 o;
        o.x = pack7(w.x) | (code0 & 0xFu) << 28;
        o.y = pack7(w.y) | (code0 >> 4) << 28;
        o.z = pack7(w.z) | (code1 & 0xFu) << 28;
        o.w = pack7(w.w) | (code1 >> 4) << 28;
        *(uint4*)&gq[(size_t)(row_base + row) * 16 + grp] = o;
    }
}

// ---------------------------------------------------------------------------
// binput0 (MFMA): graph0 = relu(fbonds @ W_i) -> packed i7 rows. K cut to 64.
// ---------------------------------------------------------------------------
__global__ __launch_bounds__(256, 4) void binput0(
    const ushort* __restrict__ fbc, const ushort* __restrict__ WT,
    uint2* __restrict__ gq_out)
{
    __shared__ ushort Xlds[32 * 25 * 8];
    __shared__ __align__(16) unsigned int qlds[32 * 32];
    __shared__ unsigned char clds[32 * 16];

    int tid = threadIdx.x;
    int bond0 = blockIdx.x * 32;           // grid = 6875, exact
    int lane = tid & 63, wv = tid >> 6;

    if (tid < 160) {                       // b = tid/5, k8 = tid%5
        int b = tid / 5, k8 = tid - b * 5;
        *(short8*)&Xlds[(b * 25 + k8) * 8] =
            *(const short8*)&fbc[(size_t)bond0 * BOND_IN + tid * 8];
    }
    if (tid < 96) {                        // zero k in [40,64): cells 5..7
        int b = tid / 3, k8 = 5 + (tid - b * 3);
        *(float4*)&Xlds[(b * 25 + k8) * 8] = float4{0.f, 0.f, 0.f, 0.f};
    }
    __syncthreads();

    int n0 = wv * 32;
    int m_lane = lane & 15, quad = lane >> 4;
    f32x4 c00 = {0,0,0,0}, c01 = {0,0,0,0}, c10 = {0,0,0,0}, c11 = {0,0,0,0};

    #pragma unroll
    for (int s = 0; s < 2; s++) {          // K = 64 covers fb (k<40) + zeros
        short8 a0 = *(const short8*)&Xlds[((m_lane)      * 25 + s * 4 + quad) * 8];
        short8 a1 = *(const short8*)&Xlds[((16 + m_lane) * 25 + s * 4 + quad) * 8];
        short8 b0 = *(const short8*)&WT[(size_t)(n0 + m_lane)      * KC + s * 32 + quad * 8];
        short8 b1 = *(const short8*)&WT[(size_t)(n0 + 16 + m_lane) * KC + s * 32 + quad * 8];
        c00 = __builtin_amdgcn_mfma_f32_16x16x32_bf16(a0, b0, c00, 0, 0, 0);
        c01 = __builtin_amdgcn_mfma_f32_16x16x32_bf16(a0, b1, c01, 0, 0, 0);
        c10 = __builtin_amdgcn_mfma_f32_16x16x32_bf16(a1, b0, c10, 0, 0, 0);
        c11 = __builtin_amdgcn_mfma_f32_16x16x32_bf16(a1, b1, c11, 0, 0, 0);
    }

    quant_epilogue7(c00, c01, c10, c11, tid, bond0, qlds, clds, gq_out);
}

// ---------------------------------------------------------------------------
// mp_round (MFMA): graph_out[b] = relu([fb[b]|nei[b]|0] @ [Wi;Wh;0])
// Gather: self-contained packed rows, 1 random line per row, no scale loads.
// ---------------------------------------------------------------------------
__global__ __launch_bounds__(256, 4) void mp_round(
    const uint2* __restrict__ msg_in,
    const ushort* __restrict__ fbc, const int* __restrict__ bgraphP,
    const ushort* __restrict__ WT,
    uint2* __restrict__ gq_out)
{
    __shared__ ushort Xlds[32 * 25 * 8];   // 800 cells x 16 B = 12800 B
    __shared__ __align__(16) unsigned int qlds[32 * 32];
    __shared__ unsigned char clds[32 * 16];

    int tid = threadIdx.x;
    int bond0 = blockIdx.x * 32;           // grid = 6875, exact
    int lane = tid & 63, wv = tid >> 6;
    int q = lane >> 4, c16 = lane & 15;

    // stage fb tile (pre-converted bf16): 160 x 16 B copies
    if (tid < 160) {
        int b = tid / 5, k8 = tid - b * 5;
        *(short8*)&Xlds[(b * 25 + k8) * 8] =
            *(const short8*)&fbc[(size_t)bond0 * BOND_IN + tid * 8];
    }
    // zero pad k in [168,192): cells 21..23
    if (tid < 96) {
        int b = tid / 3, k8 = 21 + (tid - b * 3);
        *(float4*)&Xlds[(b * 25 + k8) * 8] = float4{0.f, 0.f, 0.f, 0.f};
    }
    // gather nei: wave wv covers rows wv+4t, t = g*4+q; lane sums elements
    // [c16*8, c16*8+8) of its row -> cell 5+c16.
    #pragma unroll
    for (int g = 0; g < 2; g++) {
        int b = wv + 4 * (g * 4 + q);
        uint4 pk = gather7(msg_in, bgraphP + (size_t)(bond0 + b) * NB_PAD, c16);
        *(uint4*)&Xlds[(b * 25 + 5 + c16) * 8] = pk;
    }
    __syncthreads();

    int n0 = wv * 32;
    int m_lane = lane & 15, quad = lane >> 4;
    f32x4 c00 = {0,0,0,0}, c01 = {0,0,0,0}, c10 = {0,0,0,0}, c11 = {0,0,0,0};

    #pragma unroll
    for (int s = 0; s < KC / 32; s++) {
        short8 a0 = *(const short8*)&Xlds[((m_lane)      * 25 + s * 4 + quad) * 8];
        short8 a1 = *(const short8*)&Xlds[((16 + m_lane) * 25 + s * 4 + quad) * 8];
        short8 b0 = *(const short8*)&WT[(size_t)(n0 + m_lane)      * KC + s * 32 + quad * 8];
        short8 b1 = *(const short8*)&WT[(size_t)(n0 + 16 + m_lane) * KC + s * 32 + quad * 8];
        c00 = __builtin_amdgcn_mfma_f32_16x16x32_bf16(a0, b0, c00, 0, 0, 0);
        c01 = __builtin_amdgcn_mfma_f32_16x16x32_bf16(a0, b1, c01, 0, 0, 0);
        c10 = __builtin_amdgcn_mfma_f32_16x16x32_bf16(a1, b0, c10, 0, 0, 0);
        c11 = __builtin_amdgcn_mfma_f32_16x16x32_bf16(a1, b1, c11, 0, 0, 0);
    }

    quant_epilogue7(c00, c01, c10, c11, tid, bond0, qlds, clds, gq_out);
}

// ---------------------------------------------------------------------------
// atom_mfma: relu([nei|fatoms|0] @ WoT^T + b_o), then per-molecule partial
// sums reduced in LDS and atomicAdd'ed into out. Gather path packed-i7.
// ---------------------------------------------------------------------------
__global__ __launch_bounds__(256, 4) void atom_mfma(
    const float* __restrict__ fatoms, const uint2* __restrict__ msg,
    const int* __restrict__ agraphP, const ushort* __restrict__ WoT,
    const float* __restrict__ bo, const int* __restrict__ mol_ids,
    float* __restrict__ out)
{
    __shared__ ushort Xlds[32 * 25 * 8];
    __shared__ float htile[32 * H];
    __shared__ int mlds[32];

    int tid = threadIdx.x;
    int a0 = blockIdx.x * 32;              // grid = 3125, exact
    int lane = tid & 63, wv = tid >> 6;
    int q = lane >> 4, c16 = lane & 15;

    // fatoms: k in [128,163)
    for (int i = tid; i < 32 * ATOM_FDIM; i += 256) {
        int b = i / ATOM_FDIM, t = i - b * ATOM_FDIM;
        int k = H + t;
        Xlds[(b * 25 + (k >> 3)) * 8 + (k & 7)] = f2bf(fatoms[(size_t)a0 * ATOM_FDIM + i]);
    }
    // zero k in [163,168)
    if (tid < 160) {
        int b = tid / 5, k = 163 + (tid - b * 5);
        Xlds[(b * 25 + (k >> 3)) * 8 + (k & 7)] = 0;
    }
    // zero cells 21..23 (k in [168,192))
    if (tid < 96) {
        int b = tid / 3, k8 = 21 + (tid - b * 3);
        *(float4*)&Xlds[(b * 25 + k8) * 8] = float4{0.f, 0.f, 0.f, 0.f};
    }
    if (tid < 32) mlds[tid] = mol_ids[a0 + tid];
    // gather nei: k in [0,128) -> cell c16
    #pragma unroll
    for (int g = 0; g < 2; g++) {
        int b = wv + 4 * (g * 4 + q);
        uint4 pk = gather7(msg, agraphP + (size_t)(a0 + b) * NB_PAD, c16);
        *(uint4*)&Xlds[(b * 25 + c16) * 8] = pk;
    }
    __syncthreads();

    int n0 = wv * 32;
    int m_lane = lane & 15, quad = lane >> 4;
    float bias0 = bo[n0 + m_lane], bias1 = bo[n0 + 16 + m_lane];
    f32x4 c00 = {bias0, bias0, bias0, bias0};
    f32x4 c01 = {bias1, bias1, bias1, bias1};
    f32x4 c10 = {bias0, bias0, bias0, bias0};
    f32x4 c11 = {bias1, bias1, bias1, bias1};

    #pragma unroll
    for (int s = 0; s < KC / 32; s++) {
        short8 a0f = *(const short8*)&Xlds[((m_lane)      * 25 + s * 4 + quad) * 8];
        short8 a1f = *(const short8*)&Xlds[((16 + m_lane) * 25 + s * 4 + quad) * 8];
        short8 b0f = *(const short8*)&WoT[(size_t)(n0 + m_lane)      * KC + s * 32 + quad * 8];
        short8 b1f = *(const short8*)&WoT[(size_t)(n0 + 16 + m_lane) * KC + s * 32 + quad * 8];
        c00 = __builtin_amdgcn_mfma_f32_16x16x32_bf16(a0f, b0f, c00, 0, 0, 0);
        c01 = __builtin_amdgcn_mfma_f32_16x16x32_bf16(a0f, b1f, c01, 0, 0, 0);
        c10 = __builtin_amdgcn_mfma_f32_16x16x32_bf16(a1f, b0f, c10, 0, 0, 0);
        c11 = __builtin_amdgcn_mfma_f32_16x16x32_bf16(a1f, b1f, c11, 0, 0, 0);
    }

    #pragma unroll
    for (int r = 0; r < 4; r++) {
        int r0 = quad * 4 + r, r1 = r0 + 16;
        htile[r0 * H + n0 + m_lane]      = fmaxf(c00[r], 0.f);
        htile[r0 * H + n0 + 16 + m_lane] = fmaxf(c01[r], 0.f);
        htile[r1 * H + n0 + m_lane]      = fmaxf(c10[r], 0.f);
        htile[r1 * H + n0 + 16 + m_lane] = fmaxf(c11[r], 0.f);
    }
    __syncthreads();

    // segmented reduce over the 32-atom tile, one atomicAdd per (segment,col)
    if (tid < H) {
        int j = tid;
        float acc = 0.f;
        int cur = mlds[0];
        for (int r = 0; r < 32; r++) {
            int m = mlds[r];
            if (m != cur) {
                atomicAdd(&out[(size_t)cur * H + j], acc);
                acc = 0.f; cur = m;
            }
            acc += htile[r * H + j];
        }
        atomicAdd(&out[(size_t)cur * H + j], acc);
    }
}

// ---------------------------------------------------------------------------
// pool_div: out[m] /= count(m)  (counts via binary search on sorted mol_ids)
// ---------------------------------------------------------------------------
__global__ __launch_bounds__(128) void pool_div(
    const int* __restrict__ mol_ids, float* __restrict__ out, int n_atoms)
{
    int m = blockIdx.x;
    int j = threadIdx.x;

    int lo = 0, hi = n_atoms;
    while (lo < hi) { int mid = (lo + hi) >> 1; if (mol_ids[mid] < m) lo = mid + 1; else hi = mid; }
    int start = lo;
    hi = n_atoms;
    while (lo < hi) { int mid = (lo + hi) >> 1; if (mol_ids[mid] < m + 1) lo = mid + 1; else hi = mid; }
    int end = lo;

    out[(size_t)m * H + j] /= fmaxf((float)(end - start), 1.f);
}

// ---------------------------------------------------------------------------
extern "C" void kernel_launch(void* const* d_in, const int* in_sizes, int n_in,
                              void* d_out, int out_size, void* d_ws, size_t ws_size,
                              hipStream_t stream)
{
    const float* fatoms  = (const float*)d_in[0];
    const float* fbonds  = (const float*)d_in[1];
    const float* tree    = (const float*)d_in[2];
    const int*   agraph  = (const int*)d_in[3];
    const int*   bgraph  = (const int*)d_in[4];
    const int*   mol_ids = (const int*)d_in[5];
    const float* W_i = (const float*)d_in[7];
    const float* W_h = (const float*)d_in[8];
    const float* W_o = (const float*)d_in[9];
    const float* b_o = (const float*)d_in[10];
    float* out = (float*)d_out;

    // ws: mqA | mqB (packed rows, 30.72 MB each) | WT | WoT (48 KB each)
    //     | fbc (17.6 MB) | bgraphP (10.56 MB) | agraphP (4.8 MB)  ~95 MB
    uint2* mqA = (uint2*)d_ws;
    uint2* mqB = mqA + (size_t)N_MSG * 16;
    ushort* WT  = (ushort*)(mqB + (size_t)N_MSG * 16);
    ushort* WoT = WT + (size_t)H * KC;
    ushort* fbc = WoT + (size_t)H * KC;
    int* bgP = (int*)(fbc + (size_t)N_BONDS * BOND_IN);
    int* agP = bgP + (size_t)N_BONDS * NB_PAD;

    int prep_total = PTe + out_size;
    prep<<<(prep_total + 255) / 256, 256, 0, stream>>>(
        fbonds, W_i, W_h, W_o, bgraph, agraph, fbc, WT, WoT, bgP, agP, out, out_size);

    qtree<<<(N_MESS * 16) / 256, 256, 0, stream>>>(tree, mqA, mqB);

    binput0<<<N_BONDS / 32, 256, 0, stream>>>(fbc, WT, mqA + (size_t)N_MESS * 16);

    const uint2* tin = mqA;
    uint2* tout = mqB;
    for (int r = 0; r < DEPTH - 1; r++) {
        mp_round<<<N_BONDS / 32, 256, 0, stream>>>(tin, fbc, bgP, WT,
                                                   tout + (size_t)N_MESS * 16);
        const uint2* t1 = tin; tin = tout; tout = (uint2*)t1;
    }
    // after 5 rounds the final message table is mqB (== tin)

    atom_mfma<<<N_ATOMS / 32, 256, 0, stream>>>(fatoms, tin, agP, WoT, b_o,
                                                mol_ids, out);

    int n_mols = out_size / H;
    pool_div<<<n_mols, 128, 0, stream>>>(mol_ids, out, N_ATOMS);
}